// Round 2
// baseline (89.968 us; speedup 1.0000x reference)
//
#include <hip/hip_runtime.h>
#include <math.h>

// 6-qubit statevector sim. Each batch element is split across a 4-lane quad:
//   qubit0 -> lane bit1, qubit1 -> lane bit0, qubits 2..5 -> local index bits
//   3..0 of a 16-amplitude register array (32 VGPRs/lane for the state).
// Cross-lane ops use quad_perm DPP. Layer loop is rolled to keep code << I$.

struct cf { float r, i; };

__device__ __forceinline__ cf cmul(cf a, cf b) {
    return { fmaf(a.r, b.r, -a.i * b.i), fmaf(a.r, b.i, a.i * b.r) };
}
// acc + g*v
__device__ __forceinline__ cf cmac(cf acc, cf g, cf v) {
    acc.r = fmaf(g.r, v.r, fmaf(-g.i, v.i, acc.r));
    acc.i = fmaf(g.r, v.i, fmaf(g.i, v.r, acc.i));
    return acc;
}

// quad_perm DPP: result lane L reads source lane sel[L] within its quad.
constexpr int DPP_X1  = 0xB1; // [1,0,3,2] : xor lane bit0 (qubit1 partner)
constexpr int DPP_X2  = 0x4E; // [2,3,0,1] : xor lane bit1 (qubit0 partner)
constexpr int DPP_C01 = 0xB4; // [0,1,3,2] : swap lanes 2,3  (CNOT q0->q1)

template<int CTRL>
__device__ __forceinline__ float dppf(float v) {
    return __int_as_float(__builtin_amdgcn_mov_dpp(__float_as_int(v), CTRL, 0xF, 0xF, true));
}
template<int CTRL>
__device__ __forceinline__ cf dppc(cf v) { return { dppf<CTRL>(v.r), dppf<CTRL>(v.i) }; }

// 1q gate on a LOCAL qubit (mask M within the 16-amp array)
template<int M>
__device__ __forceinline__ void apply1q(cf* st, cf g00, cf g01, cf g10, cf g11) {
#pragma unroll
    for (int i = 0; i < 16; ++i) {
        if (i & M) continue;
        cf a = st[i], b = st[i + M];
        cf na = cmul(g00, a); na = cmac(na, g01, b);
        cf nb = cmul(g10, a); nb = cmac(nb, g11, b);
        st[i] = na; st[i + M] = nb;
    }
}

// 1q gate on a LANE qubit: partner amplitude via DPP, coeff row picked by `hi`.
template<int XCTRL>
__device__ __forceinline__ void apply1q_lane(cf* st, bool hi, cf g00, cf g01, cf g10, cf g11) {
    cf ga, gb;
    ga.r = hi ? g11.r : g00.r;  ga.i = hi ? g11.i : g00.i;
    gb.r = hi ? g10.r : g01.r;  gb.i = hi ? g10.i : g01.i;
#pragma unroll
    for (int i = 0; i < 16; ++i) {
        cf part = dppc<XCTRL>(st[i]);
        cf n = cmul(ga, st[i]);
        n = cmac(n, gb, part);
        st[i] = n;
    }
}

// CNOT with both control+target local: register swap
template<int MC, int MT>
__device__ __forceinline__ void cnot_local(cf* st) {
#pragma unroll
    for (int i = 0; i < 16; ++i) {
        if ((i & MC) && !(i & MT)) { cf t = st[i]; st[i] = st[i + MT]; st[i + MT] = t; }
    }
}

__global__ __launch_bounds__(256, 4) void qsim_kernel(
    const float* __restrict__ x, const float* __restrict__ theta,
    float* __restrict__ out) {
    // ---- per-block: 18 fused RZ*RY*RX gate matrices into LDS ----
    __shared__ float gs[18 * 8];
    const int t = threadIdx.x;
    if (t < 18) {
        const float* th = theta + t * 3;   // t = l*6 + q
        float sx, cx, sy, cy, sz, cz;
        __sincosf(0.5f * th[0], &sx, &cx);
        __sincosf(0.5f * th[1], &sy, &cy);
        __sincosf(0.5f * th[2], &sz, &cz);
        cf m00 = {  cy * cx,  sy * sx };
        cf m01 = { -sy * cx, -cy * sx };
        cf m10 = {  sy * cx, -cy * sx };
        cf m11 = {  cy * cx, -sy * sx };
        cf e0 = { cz, -sz }, e1 = { cz, sz };
        cf g00 = cmul(e0, m00), g01 = cmul(e0, m01);
        cf g10 = cmul(e1, m10), g11 = cmul(e1, m11);
        float* o = gs + t * 8;
        o[0] = g00.r; o[1] = g00.i; o[2] = g01.r; o[3] = g01.i;
        o[4] = g10.r; o[5] = g10.i; o[6] = g11.r; o[7] = g11.i;
    }
    __syncthreads();

    const int g = blockIdx.x * 256 + t;
    const int e = g >> 2;                  // batch element
    const int p = g & 3;                   // lane within quad
    const bool l1 = (p & 2) != 0;          // qubit-0 bit
    const bool l0 = (p & 1) != 0;          // qubit-1 bit

    // ---- encoding ----
    const float4* xv = reinterpret_cast<const float4*>(x + (size_t)e * 24);
    cf v0[6], v1[6];
#pragma unroll
    for (int q = 0; q < 6; ++q) {
        float4 xq = xv[q];
        float m = (xq.x + xq.y + xq.z + xq.w) * 0.25f;
        m = fminf(fmaxf(m, -6.0f), 6.0f);
        float a = m * 0.52359877559829887308f;   // pi/6
        float s2, c2, s4, c4;
        __sincosf(0.50f * a, &s2, &c2);
        __sincosf(0.25f * a, &s4, &c4);
        v0[q] = { c4 * c2, -s4 * c2 };   // (RZ(a/2) RX(a)) |0>, amp 0
        v1[q] = { s4 * s2, -c4 * s2 };   // amp 1
    }

    // qubit0/1 factor chosen by lane bits; qubits 2..5 tensor-expanded locally
    cf f0, f1;
    f0.r = l1 ? v1[0].r : v0[0].r;  f0.i = l1 ? v1[0].i : v0[0].i;
    f1.r = l0 ? v1[1].r : v0[1].r;  f1.i = l0 ? v1[1].i : v0[1].i;

    cf st[16];
    st[0] = cmul(f0, f1);
#pragma unroll
    for (int q = 2; q < 6; ++q) {
        const int m = 8 >> (q - 2);
#pragma unroll
        for (int i = 0; i < 16; i += 2 * m) {
            st[i + m] = cmul(st[i], v1[q]);   // high half first
            st[i]     = cmul(st[i], v0[q]);
        }
    }

    // ---- 3 layers (rolled: keep code well under the 32 KB I$) ----
#pragma unroll 1
    for (int l = 0; l < 3; ++l) {
        // CNOT(0,1): lanes 2<->3 exchange all amplitudes
#pragma unroll
        for (int i = 0; i < 16; ++i) st[i] = dppc<DPP_C01>(st[i]);
        // CNOT(1,2): lanes with l0==1 swap st[j] <-> st[j^8]
#pragma unroll
        for (int i = 0; i < 8; ++i) {
            cf lo = st[i], hi = st[i + 8];
            st[i].r     = l0 ? hi.r : lo.r;  st[i].i     = l0 ? hi.i : lo.i;
            st[i + 8].r = l0 ? lo.r : hi.r;  st[i + 8].i = l0 ? lo.i : hi.i;
        }
        cnot_local<8, 4>(st);   // CNOT(2,3)
        cnot_local<4, 2>(st);   // CNOT(3,4)
        cnot_local<2, 1>(st);   // CNOT(4,5)
        // CNOT(5,0): odd local j exchange across lane bit1
#pragma unroll
        for (int i = 1; i < 16; i += 2) st[i] = dppc<DPP_X2>(st[i]);

        const float* gg = gs + l * 48;
#define G4(k) cf{gg[8*(k)+0], gg[8*(k)+1]}, cf{gg[8*(k)+2], gg[8*(k)+3]}, \
              cf{gg[8*(k)+4], gg[8*(k)+5]}, cf{gg[8*(k)+6], gg[8*(k)+7]}
        apply1q_lane<DPP_X2>(st, l1, G4(0));   // qubit 0
        apply1q_lane<DPP_X1>(st, l0, G4(1));   // qubit 1
        apply1q<8>(st, G4(2));                 // qubit 2
        apply1q<4>(st, G4(3));                 // qubit 3
        apply1q<2>(st, G4(4));                 // qubit 4
        apply1q<1>(st, G4(5));                 // qubit 5
#undef G4
    }

    // ---- measurements ----
    float z0 = 0.f, z2 = 0.f, z4 = 0.f, x1s = 0.f, x3s = 0.f, x5s = 0.f;
#pragma unroll
    for (int i = 0; i < 16; ++i) {
        float pr = fmaf(st[i].r, st[i].r, st[i].i * st[i].i);
        z0 += pr;
        z2 = (i & 8) ? z2 - pr : z2 + pr;   // qubit2 = local bit3
        z4 = (i & 2) ? z4 - pr : z4 + pr;   // qubit4 = local bit1
        cf part = dppc<DPP_X1>(st[i]);      // qubit1 partner (cross-lane)
        x1s = fmaf(st[i].r, part.r, fmaf(st[i].i, part.i, x1s));
    }
    if (l1) z0 = -z0;                       // qubit0 sign = lane bit1
#pragma unroll
    for (int i = 0; i < 16; ++i) {
        if (!(i & 4)) x3s = fmaf(st[i].r, st[i + 4].r, fmaf(st[i].i, st[i + 4].i, x3s));
        if (!(i & 1)) x5s = fmaf(st[i].r, st[i + 1].r, fmaf(st[i].i, st[i + 1].i, x5s));
    }
    x3s *= 2.f; x5s *= 2.f;                 // x1s already counts both directions

    // quad butterfly reduction: all 4 lanes end with the full sums
    z0  += dppf<DPP_X1>(z0);   z0  += dppf<DPP_X2>(z0);
    z2  += dppf<DPP_X1>(z2);   z2  += dppf<DPP_X2>(z2);
    z4  += dppf<DPP_X1>(z4);   z4  += dppf<DPP_X2>(z4);
    x1s += dppf<DPP_X1>(x1s);  x1s += dppf<DPP_X2>(x1s);
    x3s += dppf<DPP_X1>(x3s);  x3s += dppf<DPP_X2>(x3s);
    x5s += dppf<DPP_X1>(x5s);  x5s += dppf<DPP_X2>(x5s);

    // out[e*8 + 0..7] = [z0, x1, z2, x3, z4, x5, z0, x1]; lane p writes p, p+4
    float o0 = l1 ? (l0 ? x3s : z2) : (l0 ? x1s : z0);
    float o1 = l1 ? (l0 ? x1s : z0) : (l0 ? x5s : z4);
    out[(size_t)e * 8 + p] = o0;
    out[(size_t)e * 8 + 4 + p] = o1;
}

extern "C" void kernel_launch(void* const* d_in, const int* in_sizes, int n_in,
                              void* d_out, int out_size, void* d_ws, size_t ws_size,
                              hipStream_t stream) {
    const float* x     = (const float*)d_in[0];   // [B, 24] f32
    const float* theta = (const float*)d_in[1];   // [3, 6, 3] f32
    float* out = (float*)d_out;                   // [B, 8] f32
    const int B = in_sizes[0] / 24;               // 131072
    const int threads = B * 4;                    // 4 lanes per element
    qsim_kernel<<<dim3(threads / 256), dim3(256), 0, stream>>>(x, theta, out);
}